// Round 10
// baseline (234.107 us; speedup 1.0000x reference)
//
#include <hip/hip_runtime.h>
#include <hip/hip_bf16.h>
#include <math.h>

#define BB 16
#define TT 256
#define CC 256
#define INNER 64
#define TPR 10
#define THD 32
#define EPSV 1e-5f

typedef __attribute__((ext_vector_type(8))) short short8;
typedef __attribute__((ext_vector_type(4))) float f32x4;
typedef __attribute__((ext_vector_type(4))) unsigned int u32x4;

__device__ __forceinline__ short f2bf(float f) {
    unsigned u = __float_as_uint(f);
    u += 0x7fffu + ((u >> 16) & 1);   // RNE
    return (short)(u >> 16);
}
__device__ __forceinline__ unsigned cvtpk(float a, float b) {
    __hip_bfloat162 h = __float22bfloat162_rn(float2{a, b});
    return *(unsigned*)&h;
}
__device__ __forceinline__ float bf_lo(unsigned u) { return __uint_as_float(u << 16); }
__device__ __forceinline__ float bf_hi(unsigned u) { return __uint_as_float(u & 0xffff0000u); }

// ---- weight image byte offsets (in ws; all LINEAR, read direct from global) ----
#define IMG_WT1  0        // [32 m][32 k] bf16 (k>=10 zero)           2KB
#define IMG_WT2  2048     // Wt2^T: [64 c][32 h] bf16                 4KB
#define IMG_WA1  6144     // Wa1^T: [64 c][64 k] bf16                 8KB
#define IMG_WA2  14336    // Wa2^T: [64 c][64 k] bf16                 8KB
#define IMG_C1   22528    // f32[32] folded BN bias                   128B
#define IMG_SZ   22656

// ---------------- prep: bf16 pre-transposed weight images + folded BN ----------------
__global__ __launch_bounds__(256) void prep_kernel(
    const float* __restrict__ Wt1, const float* __restrict__ bt1,
    const float* __restrict__ gt, const float* __restrict__ bbt,
    const float* __restrict__ mt, const float* __restrict__ vt,
    const float* __restrict__ Wt2, const float* __restrict__ Wa1,
    const float* __restrict__ Wa2, char* __restrict__ img)
{
    const int blk = blockIdx.x, t = threadIdx.x;
    if (blk == 0) {
        for (int e = t; e < 32 * 32; e += 256) {
            int m = e >> 5, k = e & 31;
            float scv = gt[m] * rsqrtf(vt[m] + EPSV);
            float v = (k < TPR) ? Wt1[k * 32 + m] * scv : 0.f;
            *(short*)(img + IMG_WT1 + m * 64 + k * 2) = f2bf(v);
        }
        if (t < 32) {
            float scv = gt[t] * rsqrtf(vt[t] + EPSV);
            ((float*)(img + IMG_C1))[t] = (bt1[t] - mt[t]) * scv + bbt[t];
        }
    } else if (blk == 1) {
        for (int e = t; e < 32 * 64; e += 256) {
            int h = e >> 6, c = e & 63;
            *(short*)(img + IMG_WT2 + c * 64 + h * 2) = f2bf(Wt2[e]);
        }
    } else {
        const float* W = (blk == 2) ? Wa1 : Wa2;
        int base = (blk == 2) ? IMG_WA1 : IMG_WA2;
        for (int e = t; e < 64 * 64; e += 256) {
            int k = e >> 6, c = e & 63;
            *(short*)(img + base + c * 128 + k * 2) = f2bf(W[e]);
        }
    }
}

// ---------------- Kernel A: y = BN(x@W1+b1); skip=y; qkv = relu(y)@Wqkv ----------------
__global__ __launch_bounds__(256) void fc1_qkv_kernel(
    const float* __restrict__ x, const float* __restrict__ W1, const float* __restrict__ b1,
    const float* __restrict__ g1, const float* __restrict__ bb1,
    const float* __restrict__ m1, const float* __restrict__ v1,
    const float* __restrict__ Wqkv,
    float* __restrict__ skip, float* __restrict__ qkv)
{
    const int ROWS = 8;
    __shared__ float xr[ROWS][CC];
    __shared__ float yr[ROWS][CC];
    const int n0 = blockIdx.x * ROWS;
    const int t = threadIdx.x;

#pragma unroll
    for (int rr = 0; rr < ROWS; ++rr)
        xr[rr][t] = x[(size_t)(n0 + rr) * CC + t];
    __syncthreads();

    float acc[ROWS];
#pragma unroll
    for (int rr = 0; rr < ROWS; ++rr) acc[rr] = 0.f;
    for (int k = 0; k < CC; ++k) {
        float wv = W1[(size_t)k * CC + t];
#pragma unroll
        for (int rr = 0; rr < ROWS; ++rr) acc[rr] = fmaf(xr[rr][k], wv, acc[rr]);
    }
    const float s1 = g1[t] * rsqrtf(v1[t] + EPSV);
    const float base = b1[t] - m1[t];
    const float bet = bb1[t];
#pragma unroll
    for (int rr = 0; rr < ROWS; ++rr) {
        float y = (acc[rr] + base) * s1 + bet;
        skip[(size_t)(n0 + rr) * CC + t] = y;
        yr[rr][t] = fmaxf(y, 0.f);
    }
    __syncthreads();

    if (t < 192) {
        float a2[ROWS];
#pragma unroll
        for (int rr = 0; rr < ROWS; ++rr) a2[rr] = 0.f;
        for (int k = 0; k < CC; ++k) {
            float wv = Wqkv[(size_t)k * 192 + t];
#pragma unroll
            for (int rr = 0; rr < ROWS; ++rr) a2[rr] = fmaf(yr[rr][k], wv, a2[rr]);
        }
#pragma unroll
        for (int rr = 0; rr < ROWS; ++rr)
            qkv[(size_t)(n0 + rr) * 192 + t] = a2[rr];
    }
}

// ---------------- Kernel B: MFMA fused vector-attention ----------------
// LDS: only the 256x128B t/h2 tile (swizzled) + reduction scratch. Weights and r
// fragments are read directly from global (img is L1/L2-resident).
#define O_TH   0        // [256 j][128B] mask-7: hid -> t -> h2 (wave-local reuse)
#define O_RED  32768    // 8 waves x 4 tm x 4 q4 x 32B
#define LDSZ   36864

__device__ __forceinline__ int swb(int row, int cb) {
    return (row << 7) + (((cb & ~15) ^ ((row & 7) << 4)) | (cb & 15));
}
__device__ __forceinline__ short8 ldTH(const char* lds, int row, int cb16) {
    return *(const short8*)(lds + O_TH + (row << 7) + (cb16 ^ ((row & 7) << 4)));
}

__global__ __launch_bounds__(512, 4) void attn_mfma_kernel(
    const float* __restrict__ r, const float* __restrict__ qkv,
    const float* __restrict__ bt2, const float* __restrict__ ba1,
    const char* __restrict__ img, float* __restrict__ agg)
{
    __shared__ __align__(16) char lds[LDSZ];
    const int n = blockIdx.x, b = n >> 8;
    const int tid = threadIdx.x;
    const int wv = tid >> 6, lane = tid & 63;
    const int lid = lane & 15, q4 = lane >> 4;
    const int kb = q4 * 16;          // byte offset of this quarter's 8-k slice in a 32-k row
    const int jt0 = wv * 2;          // wave owns j in [wv*32, wv*32+32)

    const float* kvb = qkv + (size_t)b * (TT * 192);
    const f32x4 z4 = {0.f, 0.f, 0.f, 0.f};

    // ---- cb = bt2 + q (per-ch, uniform over j -> GEMM2 C-operand); wp = bf16(v - cb)
    f32x4 cbv[4];
#pragma unroll
    for (int tm = 0; tm < 4; ++tm) {
        int ch0 = tm * 16 + q4 * 4;
        f32x4 qv = *(const f32x4*)(qkv + (size_t)n * 192 + ch0);
        f32x4 bv = *(const f32x4*)(bt2 + ch0);
#pragma unroll
        for (int g = 0; g < 4; ++g) cbv[tm][g] = qv[g] + bv[g];
    }
    uint2 wp[4][2];
#pragma unroll
    for (int tm = 0; tm < 4; ++tm) {
        int ch0 = tm * 16 + q4 * 4;
#pragma unroll
        for (int tn = 0; tn < 2; ++tn) {
            int j = (jt0 + tn) * 16 + lid;
            f32x4 v4 = *(const f32x4*)(kvb + (size_t)j * 192 + 128 + ch0);
            wp[tm][tn].x = cvtpk(v4[0] - cbv[tm][0], v4[1] - cbv[tm][1]);
            wp[tm][tn].y = cvtpk(v4[2] - cbv[tm][2], v4[3] - cbv[tm][3]);
        }
    }

    // ---- GEMM1: hid = relu(Wt1f^T @ r^T + c1); A,C from img; B direct from r
    {
        short8 a10 = *(const short8*)(img + IMG_WT1 + lid * 64 + kb);
        short8 a11 = *(const short8*)(img + IMG_WT1 + (16 + lid) * 64 + kb);
        const float* c1g = (const float*)(img + IMG_C1);
        f32x4 c1v0 = *(const f32x4*)(c1g + q4 * 4);
        f32x4 c1v1 = *(const f32x4*)(c1g + 16 + q4 * 4);
        f32x4 acc1[2][2];
#pragma unroll
        for (int tn = 0; tn < 2; ++tn) {
            int j = (jt0 + tn) * 16 + lid;
            const float* rj = r + (size_t)n * (TT * TPR) + j * TPR;
            union { short8 s; u32x4 u; } bb;
            bb.u[0] = 0u; bb.u[1] = 0u; bb.u[2] = 0u; bb.u[3] = 0u;
            if (q4 == 0) {
                float2 a0 = *(const float2*)(rj);
                float2 a1 = *(const float2*)(rj + 2);
                float2 a2 = *(const float2*)(rj + 4);
                float2 a3 = *(const float2*)(rj + 6);
                bb.u[0] = cvtpk(a0.x, a0.y); bb.u[1] = cvtpk(a1.x, a1.y);
                bb.u[2] = cvtpk(a2.x, a2.y); bb.u[3] = cvtpk(a3.x, a3.y);
            } else if (q4 == 1) {
                float2 a0 = *(const float2*)(rj + 8);
                bb.u[0] = cvtpk(a0.x, a0.y);
            }
            acc1[0][tn] = __builtin_amdgcn_mfma_f32_16x16x32_bf16(a10, bb.s, c1v0, 0, 0, 0);
            acc1[1][tn] = __builtin_amdgcn_mfma_f32_16x16x32_bf16(a11, bb.s, c1v1, 0, 0, 0);
        }
#pragma unroll
        for (int tm = 0; tm < 2; ++tm)
#pragma unroll
            for (int tn = 0; tn < 2; ++tn) {
                int j = (jt0 + tn) * 16 + lid;
                uint2 w;
                w.x = cvtpk(fmaxf(acc1[tm][tn][0], 0.f), fmaxf(acc1[tm][tn][1], 0.f));
                w.y = cvtpk(fmaxf(acc1[tm][tn][2], 0.f), fmaxf(acc1[tm][tn][3], 0.f));
                *(uint2*)(lds + swb(j, tm * 32 + q4 * 8)) = w;
            }
    }

    // ---- GEMM2: R1 = Wt2^T @ hid^T + (bt2+q); per tm-half with k prefetch;
    //      t = R1 - k -> bf16 LDS;  vvp = wp + R1 -> bf16 regs
    uint2 vvp[4][2];
    {
        short8 bfh[2];
#pragma unroll
        for (int tn = 0; tn < 2; ++tn)
            bfh[tn] = ldTH(lds, (jt0 + tn) * 16 + lid, kb);
#pragma unroll
        for (int hf = 0; hf < 2; ++hf) {
            const int tA = hf * 2, tB = hf * 2 + 1;
            short8 awA = *(const short8*)(img + IMG_WT2 + (tA * 16 + lid) * 64 + kb);
            short8 awB = *(const short8*)(img + IMG_WT2 + (tB * 16 + lid) * 64 + kb);
            f32x4 kA[2], kB[2];
#pragma unroll
            for (int tn = 0; tn < 2; ++tn) {
                int j = (jt0 + tn) * 16 + lid;
                kA[tn] = *(const f32x4*)(kvb + (size_t)j * 192 + 64 + tA * 16 + q4 * 4);
                kB[tn] = *(const f32x4*)(kvb + (size_t)j * 192 + 64 + tB * 16 + q4 * 4);
            }
            f32x4 rA[2], rB[2];
#pragma unroll
            for (int tn = 0; tn < 2; ++tn) {
                rA[tn] = __builtin_amdgcn_mfma_f32_16x16x32_bf16(awA, bfh[tn], cbv[tA], 0, 0, 0);
                rB[tn] = __builtin_amdgcn_mfma_f32_16x16x32_bf16(awB, bfh[tn], cbv[tB], 0, 0, 0);
            }
#pragma unroll
            for (int tn = 0; tn < 2; ++tn) {
                int j = (jt0 + tn) * 16 + lid;
                uint2 w;
                w.x = cvtpk(rA[tn][0] - kA[tn][0], rA[tn][1] - kA[tn][1]);
                w.y = cvtpk(rA[tn][2] - kA[tn][2], rA[tn][3] - kA[tn][3]);
                *(uint2*)(lds + swb(j, tA * 32 + q4 * 8)) = w;
                w.x = cvtpk(rB[tn][0] - kB[tn][0], rB[tn][1] - kB[tn][1]);
                w.y = cvtpk(rB[tn][2] - kB[tn][2], rB[tn][3] - kB[tn][3]);
                *(uint2*)(lds + swb(j, tB * 32 + q4 * 8)) = w;
                vvp[tA][tn].x = cvtpk(bf_lo(wp[tA][tn].x) + rA[tn][0], bf_hi(wp[tA][tn].x) + rA[tn][1]);
                vvp[tA][tn].y = cvtpk(bf_lo(wp[tA][tn].y) + rA[tn][2], bf_hi(wp[tA][tn].y) + rA[tn][3]);
                vvp[tB][tn].x = cvtpk(bf_lo(wp[tB][tn].x) + rB[tn][0], bf_hi(wp[tB][tn].x) + rB[tn][1]);
                vvp[tB][tn].y = cvtpk(bf_lo(wp[tB][tn].y) + rB[tn][2], bf_hi(wp[tB][tn].y) + rB[tn][3]);
            }
        }
    }

    // ---- GEMM3: h2 = relu(Wa1^T @ t^T + ba1)
    f32x4 acc[4][2];
#pragma unroll
    for (int tm = 0; tm < 4; ++tm) {
        f32x4 bv = *(const f32x4*)(ba1 + tm * 16 + q4 * 4);
#pragma unroll
        for (int tn = 0; tn < 2; ++tn) acc[tm][tn] = bv;
    }
#pragma unroll
    for (int ks = 0; ks < 2; ++ks) {
        short8 aw[4];
#pragma unroll
        for (int tm = 0; tm < 4; ++tm)
            aw[tm] = *(const short8*)(img + IMG_WA1 + (tm * 16 + lid) * 128 + ks * 64 + kb);
#pragma unroll
        for (int tn = 0; tn < 2; ++tn) {
            short8 bt = ldTH(lds, (jt0 + tn) * 16 + lid, ks * 64 + kb);
#pragma unroll
            for (int tm = 0; tm < 4; ++tm)
                acc[tm][tn] = __builtin_amdgcn_mfma_f32_16x16x32_bf16(aw[tm], bt, acc[tm][tn], 0, 0, 0);
        }
    }
#pragma unroll
    for (int tm = 0; tm < 4; ++tm)
#pragma unroll
        for (int tn = 0; tn < 2; ++tn) {
            int j = (jt0 + tn) * 16 + lid;
            uint2 w;
            w.x = cvtpk(fmaxf(acc[tm][tn][0], 0.f), fmaxf(acc[tm][tn][1], 0.f));
            w.y = cvtpk(fmaxf(acc[tm][tn][2], 0.f), fmaxf(acc[tm][tn][3], 0.f));
            *(uint2*)(lds + swb(j, tm * 32 + q4 * 8)) = w;
        }

    // ---- GEMM4: sim = Wa2^T @ h2^T (ba2 cancels in softmax)
#pragma unroll
    for (int tm = 0; tm < 4; ++tm)
#pragma unroll
        for (int tn = 0; tn < 2; ++tn) acc[tm][tn] = z4;
#pragma unroll
    for (int ks = 0; ks < 2; ++ks) {
        short8 aw[4];
#pragma unroll
        for (int tm = 0; tm < 4; ++tm)
            aw[tm] = *(const short8*)(img + IMG_WA2 + (tm * 16 + lid) * 128 + ks * 64 + kb);
#pragma unroll
        for (int tn = 0; tn < 2; ++tn) {
            short8 bt = ldTH(lds, (jt0 + tn) * 16 + lid, ks * 64 + kb);
#pragma unroll
            for (int tm = 0; tm < 4; ++tm)
                acc[tm][tn] = __builtin_amdgcn_mfma_f32_16x16x32_bf16(aw[tm], bt, acc[tm][tn], 0, 0, 0);
        }
    }

    // ---- softmax over j + weighted vv sum
#pragma unroll
    for (int tm = 0; tm < 4; ++tm) {
        f32x4 num = z4, den = z4;
#pragma unroll
        for (int tn = 0; tn < 2; ++tn) {
            float vf0 = bf_lo(vvp[tm][tn].x), vf1 = bf_hi(vvp[tm][tn].x);
            float vf2 = bf_lo(vvp[tm][tn].y), vf3 = bf_hi(vvp[tm][tn].y);
            float e0 = __expf(acc[tm][tn][0]);
            float e1 = __expf(acc[tm][tn][1]);
            float e2 = __expf(acc[tm][tn][2]);
            float e3 = __expf(acc[tm][tn][3]);
            den[0] += e0; num[0] = fmaf(e0, vf0, num[0]);
            den[1] += e1; num[1] = fmaf(e1, vf1, num[1]);
            den[2] += e2; num[2] = fmaf(e2, vf2, num[2]);
            den[3] += e3; num[3] = fmaf(e3, vf3, num[3]);
        }
#pragma unroll
        for (int ofs = 1; ofs < 16; ofs <<= 1) {
#pragma unroll
            for (int g = 0; g < 4; ++g) {
                num[g] += __shfl_xor(num[g], ofs);
                den[g] += __shfl_xor(den[g], ofs);
            }
        }
        if (lid == 0) {
            int base = O_RED + ((wv * 4 + tm) * 4 + q4) * 32;
            *(f32x4*)(lds + base) = num;
            *(f32x4*)(lds + base + 16) = den;
        }
    }
    __syncthreads();

    if (tid < 64) {
        int tm = tid >> 4, qq = (tid >> 2) & 3, g = tid & 3;
        float nn = 0.f, dd = 0.f;
#pragma unroll
        for (int w = 0; w < 8; ++w) {
            int base = O_RED + ((w * 4 + tm) * 4 + qq) * 32 + g * 4;
            nn += *(const float*)(lds + base);
            dd += *(const float*)(lds + base + 16);
        }
        agg[(size_t)n * 64 + tid] = nn / dd;
    }
}

// ---------------- Kernel C: out = relu(BN(agg@W2+b2) + skip) ----------------
__global__ __launch_bounds__(256) void fc2_kernel(
    const float* __restrict__ agg, const float* __restrict__ W2, const float* __restrict__ b2,
    const float* __restrict__ g2, const float* __restrict__ bb2,
    const float* __restrict__ m2, const float* __restrict__ v2,
    const float* __restrict__ skip, float* __restrict__ out)
{
    const int ROWS = 8;
    __shared__ float ar[ROWS][INNER];
    const int n0 = blockIdx.x * ROWS;
    const int t = threadIdx.x;

    for (int idx = t; idx < ROWS * INNER; idx += 256)
        ((float*)ar)[idx] = agg[(size_t)n0 * INNER + idx];
    __syncthreads();

    const float s2 = g2[t] * rsqrtf(v2[t] + EPSV);
    const float base = b2[t] - m2[t];
    const float bet = bb2[t];

    float accv[ROWS];
#pragma unroll
    for (int rr = 0; rr < ROWS; ++rr) accv[rr] = 0.f;
    for (int k = 0; k < INNER; ++k) {
        float wv = W2[(size_t)k * CC + t];
#pragma unroll
        for (int rr = 0; rr < ROWS; ++rr) accv[rr] = fmaf(ar[rr][k], wv, accv[rr]);
    }
#pragma unroll
    for (int rr = 0; rr < ROWS; ++rr) {
        float y = (accv[rr] + base) * s2 + bet;
        out[(size_t)(n0 + rr) * CC + t] =
            fmaxf(y + skip[(size_t)(n0 + rr) * CC + t], 0.f);
    }
}

extern "C" void kernel_launch(void* const* d_in, const int* in_sizes, int n_in,
                              void* d_out, int out_size, void* d_ws, size_t ws_size,
                              hipStream_t stream)
{
    const float* x   = (const float*)d_in[0];
    const float* r   = (const float*)d_in[1];
    const float* W1  = (const float*)d_in[2];
    const float* b1  = (const float*)d_in[3];
    const float* g1  = (const float*)d_in[4];
    const float* bb1 = (const float*)d_in[5];
    const float* m1  = (const float*)d_in[6];
    const float* v1  = (const float*)d_in[7];
    const float* Wqkv= (const float*)d_in[8];
    const float* Wt1 = (const float*)d_in[9];
    const float* bt1 = (const float*)d_in[10];
    const float* gt  = (const float*)d_in[11];
    const float* bbt = (const float*)d_in[12];
    const float* mt  = (const float*)d_in[13];
    const float* vt  = (const float*)d_in[14];
    const float* Wt2 = (const float*)d_in[15];
    const float* bt2 = (const float*)d_in[16];
    const float* Wa1 = (const float*)d_in[17];
    const float* ba1 = (const float*)d_in[18];
    const float* Wa2 = (const float*)d_in[19];
    const float* W2  = (const float*)d_in[21];
    const float* b2  = (const float*)d_in[22];
    const float* g2  = (const float*)d_in[23];
    const float* bb2 = (const float*)d_in[24];
    const float* m2  = (const float*)d_in[25];
    const float* v2  = (const float*)d_in[26];
    float* out = (float*)d_out;

    const int N = BB * TT;                 // 4096 rows
    float* skip = (float*)d_ws;            // N*256 floats
    float* qkv  = skip + (size_t)N * CC;   // N*192 floats
    float* agg  = qkv  + (size_t)N * 192;  // N*64  floats
    char*  img  = (char*)(agg + (size_t)N * 64);  // 22.7KB weight image

    prep_kernel<<<dim3(4), dim3(256), 0, stream>>>(
        Wt1, bt1, gt, bbt, mt, vt, Wt2, Wa1, Wa2, img);
    fc1_qkv_kernel<<<dim3(N / 8), dim3(256), 0, stream>>>(
        x, W1, b1, g1, bb1, m1, v1, Wqkv, skip, qkv);
    attn_mfma_kernel<<<dim3(N), dim3(512), 0, stream>>>(
        r, qkv, bt2, ba1, img, agg);
    fc2_kernel<<<dim3(N / 8), dim3(256), 0, stream>>>(
        agg, W2, b2, g2, bb2, m2, v2, skip, out);
}